// Round 3
// baseline (248.401 us; speedup 1.0000x reference)
//
#include <hip/hip_runtime.h>
#include <stdint.h>

// Shapes (fixed by the problem)
#define Bn 256
#define Un 128
#define Pn 64
#define Hn 768
#define Ototal 192   // 128 row-logit outputs + 64 col-logit outputs
#define KC 16        // split-K chunks in phase B (K=8192 -> 512 each)

#define CH 64        // floats per H-chunk in phaseA
#define NCH 12       // 768 / 64
#define LDU 72       // phaseA LDS row stride (ushorts)
#define LDB 56       // phaseB LDS row stride (ushorts)

typedef short s4v __attribute__((ext_vector_type(4)));
typedef short s8v __attribute__((ext_vector_type(8)));
typedef float f4v __attribute__((ext_vector_type(4)));

__device__ __forceinline__ short f2bf(float x) {
  union { float f; uint32_t u; } c; c.f = x;
  uint32_t r = (c.u + 0x7fffu + ((c.u >> 16) & 1u)) >> 16;  // RNE
  return (short)(r & 0xffffu);
}

// ---------------------------------------------------------------------------
// Kernel 1: pack weights into bf16 W'[o][k], o<128: w_utt[o,i,j]; o>=128:
// w_pheno[o-128, j, i]  (k = i*64 + j) so both logit einsums share one GEMM.
// ---------------------------------------------------------------------------
__global__ void __launch_bounds__(256) convW(const float* __restrict__ w_utt,
                                             const float* __restrict__ w_ph,
                                             ushort* __restrict__ Wbf) {
  __shared__ float tile[64 * 129];   // [j][i], +1 pad -> conflict-free columns
  const int bx = blockIdx.x;
  const int t = threadIdx.x;
  if (bx < 4096) {
    int idx = bx * 256 + t;                       // 0 .. 128*8192-1
    Wbf[idx] = (ushort)f2bf(w_utt[idx]);
    return;
  }
  const int oc = bx - 4096;                       // 0..63
  const float* src = w_ph + (size_t)oc * 8192;    // [j][i] = 64 x 128
#pragma unroll
  for (int itr = 0; itr < 8; ++itr) {
    int idx = itr * 1024 + t * 4;                 // 4 consecutive i of one j-row
    int j = idx >> 7, i = idx & 127;
    float4 v = *(const float4*)(src + idx);       // coalesced 16B
    tile[j * 129 + i + 0] = v.x;
    tile[j * 129 + i + 1] = v.y;
    tile[j * 129 + i + 2] = v.z;
    tile[j * 129 + i + 3] = v.w;
  }
  __syncthreads();
  const size_t obase = (size_t)(128 + oc) * 8192;
#pragma unroll
  for (int itr = 0; itr < 8; ++itr) {
    int k = itr * 1024 + t * 4;                   // k = i*64 + j
    int i = k >> 6, j = k & 63;
    s4v o4 = { f2bf(tile[(j + 0) * 129 + i]),
               f2bf(tile[(j + 1) * 129 + i]),
               f2bf(tile[(j + 2) * 129 + i]),
               f2bf(tile[(j + 3) * 129 + i]) };
    *(s4v*)&Wbf[obase + k] = o4;                  // coalesced 8B
  }
}

// ---------------------------------------------------------------------------
// Kernel 2: per-batch cosine-sim matrix. c[b,i,j] = (u_i.p_j)*inu_i*inp_j
// 1024 threads = 16 waves. Manually 2x-unrolled double-buffer: NAMED register
// sets (no arrays -> no scratch spill possible), one barrier per chunk.
// ---------------------------------------------------------------------------
__global__ void __launch_bounds__(1024) phaseA(const float* __restrict__ utt,
                                               const float* __restrict__ ph,
                                               ushort* __restrict__ Cbf) {
  const int b = blockIdx.x;
  const int t = threadIdx.x;          // 0..1023
  const int w = t >> 6, l = t & 63;

  __shared__ short uA[2][Un * LDU];
  __shared__ short pB[2][Pn * LDU];
  __shared__ float s_inu[Un];
  __shared__ float s_inp[Pn];

  const int ur = t >> 3;              // u row 0..127 (8 threads/row)
  const int uc = (t & 7) * 8;         // u col start (floats)
  const int pr = t >> 4;              // p row 0..63 (16 threads/row)
  const int pc = (t & 15) * 4;        // p col start (floats)

  const size_t rstride = (size_t)Bn * Hn;
  const float* ubase = utt + (size_t)b * Hn + (size_t)ur * rstride + uc;
  const float* pbase = ph  + (size_t)b * Hn + (size_t)pr * rstride + pc;

  // named double-buffer registers (NO arrays)
  float4 uA0, uA1, pA0;   // even chunks
  float4 uB0, uB1, pB0;   // odd chunks
  uA0 = *(const float4*)(ubase + 0);
  uA1 = *(const float4*)(ubase + 4);
  pA0 = *(const float4*)(pbase + 0);
  uB0 = *(const float4*)(ubase + CH);
  uB1 = *(const float4*)(ubase + CH + 4);
  pB0 = *(const float4*)(pbase + CH);

  float ssu = 0.f, ssp = 0.f;
  f4v zero4 = {0.f, 0.f, 0.f, 0.f};
  f4v acc0 = zero4, acc1 = zero4;

  const int m  = l & 15;
  const int ko = (l >> 4) * 8;
  const int it = w & 7;               // i-tile (16 rows)
  const int jp = w >> 3;              // j-half (32 cols)

  const int ua_w = ur * LDU + uc;
  const int pb_w = pr * LDU + pc;

#pragma unroll
  for (int c = 0; c < NCH; c += 2) {
    // ---------------- even chunk c -> buffer 0 ----------------
    {
      float4 a0 = uA0, a1 = uA1, p0 = pA0;
      ssu += a0.x*a0.x + a0.y*a0.y + a0.z*a0.z + a0.w*a0.w
           + a1.x*a1.x + a1.y*a1.y + a1.z*a1.z + a1.w*a1.w;
      ssp += p0.x*p0.x + p0.y*p0.y + p0.z*p0.z + p0.w*p0.w;
      if (c + 2 < NCH) {
        uA0 = *(const float4*)(ubase + (c + 2) * CH);
        uA1 = *(const float4*)(ubase + (c + 2) * CH + 4);
        pA0 = *(const float4*)(pbase + (c + 2) * CH);
      }
      s8v au = { f2bf(a0.x), f2bf(a0.y), f2bf(a0.z), f2bf(a0.w),
                 f2bf(a1.x), f2bf(a1.y), f2bf(a1.z), f2bf(a1.w) };
      s4v pp = { f2bf(p0.x), f2bf(p0.y), f2bf(p0.z), f2bf(p0.w) };
      *(s8v*)&uA[0][ua_w] = au;
      *(s4v*)&pB[0][pb_w] = pp;
      __syncthreads();
      const short* ab = &uA[0][(it * 16 + m) * LDU + ko];
      const short* bb = &pB[0][(jp * 32 + m) * LDU + ko];
#pragma unroll
      for (int ks = 0; ks < 2; ++ks) {
        s8v af = *(const s8v*)(ab + ks * 32);
        s8v bf0 = *(const s8v*)(bb + ks * 32);
        s8v bf1 = *(const s8v*)(bb + 16 * LDU + ks * 32);
        acc0 = __builtin_amdgcn_mfma_f32_16x16x32_bf16(af, bf0, acc0, 0, 0, 0);
        acc1 = __builtin_amdgcn_mfma_f32_16x16x32_bf16(af, bf1, acc1, 0, 0, 0);
      }
    }
    // ---------------- odd chunk c+1 -> buffer 1 ----------------
    {
      float4 a0 = uB0, a1 = uB1, p0 = pB0;
      ssu += a0.x*a0.x + a0.y*a0.y + a0.z*a0.z + a0.w*a0.w
           + a1.x*a1.x + a1.y*a1.y + a1.z*a1.z + a1.w*a1.w;
      ssp += p0.x*p0.x + p0.y*p0.y + p0.z*p0.z + p0.w*p0.w;
      if (c + 3 < NCH) {
        uB0 = *(const float4*)(ubase + (c + 3) * CH);
        uB1 = *(const float4*)(ubase + (c + 3) * CH + 4);
        pB0 = *(const float4*)(pbase + (c + 3) * CH);
      }
      s8v au = { f2bf(a0.x), f2bf(a0.y), f2bf(a0.z), f2bf(a0.w),
                 f2bf(a1.x), f2bf(a1.y), f2bf(a1.z), f2bf(a1.w) };
      s4v pp = { f2bf(p0.x), f2bf(p0.y), f2bf(p0.z), f2bf(p0.w) };
      *(s8v*)&uA[1][ua_w] = au;
      *(s4v*)&pB[1][pb_w] = pp;
      __syncthreads();
      const short* ab = &uA[1][(it * 16 + m) * LDU + ko];
      const short* bb = &pB[1][(jp * 32 + m) * LDU + ko];
#pragma unroll
      for (int ks = 0; ks < 2; ++ks) {
        s8v af = *(const s8v*)(ab + ks * 32);
        s8v bf0 = *(const s8v*)(bb + ks * 32);
        s8v bf1 = *(const s8v*)(bb + 16 * LDU + ks * 32);
        acc0 = __builtin_amdgcn_mfma_f32_16x16x32_bf16(af, bf0, acc0, 0, 0, 0);
        acc1 = __builtin_amdgcn_mfma_f32_16x16x32_bf16(af, bf1, acc1, 0, 0, 0);
      }
    }
  }

  // row sumsq reductions (threads sharing a row are adjacent lanes)
  ssu += __shfl_xor(ssu, 4); ssu += __shfl_xor(ssu, 2); ssu += __shfl_xor(ssu, 1);
  ssp += __shfl_xor(ssp, 8); ssp += __shfl_xor(ssp, 4);
  ssp += __shfl_xor(ssp, 2); ssp += __shfl_xor(ssp, 1);
  if ((t & 7) == 0)  s_inu[ur] = 1.f / fmaxf(sqrtf(ssu), 1e-8f);
  if ((t & 15) == 0) s_inp[pr] = 1.f / fmaxf(sqrtf(ssp), 1e-8f);
  __syncthreads();

  // epilogue: scale, store bf16 C[b][i][j]
  // D layout (verified m89/m91): col = lane&15, row = (lane>>4)*4 + reg
  const int cl = l & 15;
  const int rq = (l >> 4) * 4;
#pragma unroll
  for (int jt = 0; jt < 2; ++jt) {
    int j = jp * 32 + jt * 16 + cl;
    float sj = s_inp[j];
    f4v a = (jt == 0) ? acc0 : acc1;
#pragma unroll
    for (int r = 0; r < 4; ++r) {
      int il = it * 16 + rq + r;
      float v = a[r] * s_inu[il] * sj;
      Cbf[((size_t)b * Un + il) * Pn + j] = (ushort)f2bf(v);
    }
  }
}

// ---------------------------------------------------------------------------
// Kernel 3: logits GEMM, M=256 batches, N=192 outputs, K=8192, split-K.
// grid = (kc=16, mt=4, nt=3); 64x64 tile per block; partial[kc][b][o] fp32.
// ---------------------------------------------------------------------------
__global__ void __launch_bounds__(256) phaseB(const ushort* __restrict__ Cbf,
                                              const ushort* __restrict__ Wbf,
                                              float* __restrict__ partial) {
  const int kc = blockIdx.x;
  const int mt = blockIdx.y;
  const int nt = blockIdx.z;
  const int t = threadIdx.x;
  const int w = t >> 6, l = t & 63;

  __shared__ short Ab[64 * LDB];
  __shared__ short Bb[64 * LDB];

  const int row = t >> 2;          // 0..63
  const int ko8 = (t & 3) * 8;

  f4v zero4 = {0.f, 0.f, 0.f, 0.f};
  f4v acc[4] = {zero4, zero4, zero4, zero4};

  const ushort* Ag = Cbf + (size_t)(mt * 64 + row) * 8192 + kc * 512 + ko8;
  const ushort* Bg = Wbf + (size_t)(nt * 64 + row) * 8192 + kc * 512 + ko8;
  const int m  = l & 15;
  const int ko = (l >> 4) * 8;

  for (int c = 0; c < 16; ++c) {
    s8v av = *(const s8v*)(Ag + c * 32);
    s8v bv = *(const s8v*)(Bg + c * 32);
    __syncthreads();
    *(s8v*)&Ab[row * LDB + ko8] = av;
    *(s8v*)&Bb[row * LDB + ko8] = bv;
    __syncthreads();
    s8v af = *(const s8v*)&Ab[(16 * w + m) * LDB + ko];
#pragma unroll
    for (int jt = 0; jt < 4; ++jt) {
      s8v bf = *(const s8v*)&Bb[(16 * jt + m) * LDB + ko];
      acc[jt] = __builtin_amdgcn_mfma_f32_16x16x32_bf16(af, bf, acc[jt], 0, 0, 0);
    }
  }

  const int rq = (l >> 4) * 4;
#pragma unroll
  for (int jt = 0; jt < 4; ++jt) {
    int og = nt * 64 + 16 * jt + (l & 15);
#pragma unroll
    for (int r = 0; r < 4; ++r) {
      int bg = mt * 64 + 16 * w + rq + r;
      partial[((size_t)kc * Bn + bg) * Ototal + og] = acc[jt][r];
    }
  }
}

// ---------------------------------------------------------------------------
// Kernel 4: reduce split-K partials + bias + dual-group softmax.
// ---------------------------------------------------------------------------
__global__ void __launch_bounds__(192) phaseC(const float* __restrict__ partial,
                                              const float* __restrict__ b_utt,
                                              const float* __restrict__ b_ph,
                                              float* __restrict__ out) {
  const int b = blockIdx.x;
  const int t = threadIdx.x;      // 0..191
  const int w = t >> 6, l = t & 63;

  float v = 0.f;
#pragma unroll
  for (int kc = 0; kc < KC; ++kc)
    v += partial[((size_t)kc * Bn + b) * Ototal + t];
  v += (t < Un) ? b_utt[t] : b_ph[t - Un];

  __shared__ float red[3];
  float mx = v;
  for (int o = 32; o >= 1; o >>= 1) mx = fmaxf(mx, __shfl_xor(mx, o));
  if (l == 0) red[w] = mx;
  __syncthreads();
  float gmax = (t < Un) ? fmaxf(red[0], red[1]) : red[2];
  float e = expf(v - gmax);
  float s = e;
  for (int o = 32; o >= 1; o >>= 1) s += __shfl_xor(s, o);
  __syncthreads();
  if (l == 0) red[w] = s;
  __syncthreads();
  float gs = (t < Un) ? (red[0] + red[1]) : red[2];
  float r = e / gs;
  if (t < Un) out[(size_t)b * Un + t] = r;
  else        out[(size_t)Bn * Un + (size_t)b * Pn + (t - Un)] = r;
}

// ---------------------------------------------------------------------------
extern "C" void kernel_launch(void* const* d_in, const int* in_sizes, int n_in,
                              void* d_out, int out_size, void* d_ws, size_t ws_size,
                              hipStream_t stream) {
  const float* utt   = (const float*)d_in[0];  // [128,256,768]
  const float* ph    = (const float*)d_in[1];  // [64,256,768]
  const float* w_utt = (const float*)d_in[2];  // [128,128,64]
  const float* b_utt = (const float*)d_in[3];  // [128]
  const float* w_ph  = (const float*)d_in[4];  // [64,64,128]
  const float* b_ph  = (const float*)d_in[5];  // [64]

  char* ws = (char*)d_ws;
  ushort* Cbf     = (ushort*)(ws);                 // 256*128*64*2  = 4 MiB
  ushort* Wbf     = (ushort*)(ws + 4194304);       // 192*8192*2   = 3 MiB
  float*  partial = (float*)(ws + 7340032);        // 16*256*192*4 = 3 MiB

  convW <<<dim3(4096 + 64), dim3(256), 0, stream>>>(w_utt, w_ph, Wbf);
  phaseA<<<dim3(Bn), dim3(1024), 0, stream>>>(utt, ph, Cbf);
  phaseB<<<dim3(KC, 4, 3), dim3(256), 0, stream>>>(Cbf, Wbf, partial);
  phaseC<<<dim3(Bn), dim3(192), 0, stream>>>(partial, b_utt, b_ph, (float*)d_out);
}

// Round 4
// 211.654 us; speedup vs baseline: 1.1736x; 1.1736x over previous
//
#include <hip/hip_runtime.h>
#include <stdint.h>

// Shapes (fixed by the problem)
#define Bn 256
#define Un 128
#define Pn 64
#define Hn 768
#define Ototal 192   // 128 row-logit outputs + 64 col-logit outputs
#define KC 16        // split-K chunks in phase B (K=8192 -> 512 each)

#define LDU 40       // phaseA LDS row stride (ushorts): 80B = 5*16 (b128-aligned)
#define LDB 72       // phaseB LDS row stride (ushorts): 144B = 9*16 (b128-aligned)

typedef short s4v __attribute__((ext_vector_type(4)));
typedef short s8v __attribute__((ext_vector_type(8)));
typedef float f4v __attribute__((ext_vector_type(4)));

__device__ __forceinline__ short f2bf(float x) {
  union { float f; uint32_t u; } c; c.f = x;
  uint32_t r = (c.u + 0x7fffu + ((c.u >> 16) & 1u)) >> 16;  // RNE
  return (short)(r & 0xffffu);
}

// ---------------------------------------------------------------------------
// Kernel 1: pack weights into bf16 W'[o][k], o<128: w_utt[o,i,j]; o>=128:
// w_pheno[o-128, j, i]  (k = i*64 + j) so both logit einsums share one GEMM.
// ---------------------------------------------------------------------------
__global__ void __launch_bounds__(256) convW(const float* __restrict__ w_utt,
                                             const float* __restrict__ w_ph,
                                             ushort* __restrict__ Wbf) {
  __shared__ float tile[64 * 129];   // [j][i], +1 pad -> conflict-free columns
  const int bx = blockIdx.x;
  const int t = threadIdx.x;
  if (bx < 4096) {
    int idx = bx * 256 + t;                       // 0 .. 128*8192-1
    Wbf[idx] = (ushort)f2bf(w_utt[idx]);
    return;
  }
  const int oc = bx - 4096;                       // 0..63
  const float* src = w_ph + (size_t)oc * 8192;    // [j][i] = 64 x 128
#pragma unroll
  for (int itr = 0; itr < 8; ++itr) {
    int idx = itr * 1024 + t * 4;                 // 4 consecutive i of one j-row
    int j = idx >> 7, i = idx & 127;
    float4 v = *(const float4*)(src + idx);       // coalesced 16B
    tile[j * 129 + i + 0] = v.x;
    tile[j * 129 + i + 1] = v.y;
    tile[j * 129 + i + 2] = v.z;
    tile[j * 129 + i + 3] = v.w;
  }
  __syncthreads();
  const size_t obase = (size_t)(128 + oc) * 8192;
#pragma unroll
  for (int itr = 0; itr < 8; ++itr) {
    int k = itr * 1024 + t * 4;                   // k = i*64 + j
    int i = k >> 6, j = k & 63;
    s4v o4 = { f2bf(tile[(j + 0) * 129 + i]),
               f2bf(tile[(j + 1) * 129 + i]),
               f2bf(tile[(j + 2) * 129 + i]),
               f2bf(tile[(j + 3) * 129 + i]) };
    *(s4v*)&Wbf[obase + k] = o4;                  // coalesced 8B
  }
}

// ---------------------------------------------------------------------------
// Kernel 2: cosine-sim matrix, 2 blocks/batch (grid 512 -> 2 blocks/CU so
// one block's barrier drain is hidden by the other block's loads).
// Block (b, half): rows i in [half*64, half*64+64) x all 64 j.
// 512 thr / 8 waves, round-1 spill-free structure (~35 VGPR, 1 f4 u + 1 f4 p
// prefetch per thread). c[b,i,j] = (u_i.p_j)*inu_i*inp_j (norms factored out).
// ---------------------------------------------------------------------------
__global__ void __launch_bounds__(512) phaseA(const float* __restrict__ utt,
                                              const float* __restrict__ ph,
                                              ushort* __restrict__ Cbf) {
  const int bx = blockIdx.x;
  const int b = bx >> 1, half = bx & 1;
  const int t = threadIdx.x;          // 0..511
  const int w = t >> 6, l = t & 63;

  __shared__ short uA[64 * LDU];      // 5 KiB
  __shared__ short pB[64 * LDU];      // 5 KiB
  __shared__ float s_inu[64];
  __shared__ float s_inp[64];

  const int r  = t >> 3;              // 0..63 (row for both u-half and p)
  const int cc = (t & 7) * 4;         // col start within 32-float chunk

  const size_t rstride = (size_t)Bn * Hn;
  const float* ubase = utt + (size_t)b * Hn + (size_t)(half * 64 + r) * rstride + cc;
  const float* pbase = ph  + (size_t)b * Hn + (size_t)r * rstride + cc;

  float4 ru = *(const float4*)ubase;  // chunk-0 prefetch
  float4 rp = *(const float4*)pbase;

  float ssu = 0.f, ssp = 0.f;
  f4v zero4 = {0.f, 0.f, 0.f, 0.f};
  f4v acc0 = zero4, acc1 = zero4;

  const int m  = l & 15;
  const int ko = (l >> 4) * 8;
  const int it = w & 3;               // i-tile (16 rows), 0..3
  const int jp = w >> 2;              // j-half (32 cols), 0..1
  const int lw = r * LDU + (t & 7) * 4;   // LDS write offset (elements)

  const short* ab = &uA[(it * 16 + m) * LDU + ko];
  const short* bb = &pB[(jp * 32 + m) * LDU + ko];

  for (int c = 0; c < 24; ++c) {
    __syncthreads();                  // prev MFMA reads done before overwrite
    float4 a = ru, p0 = rp;
    ssu += a.x*a.x + a.y*a.y + a.z*a.z + a.w*a.w;
    ssp += p0.x*p0.x + p0.y*p0.y + p0.z*p0.z + p0.w*p0.w;
    s4v au = { f2bf(a.x),  f2bf(a.y),  f2bf(a.z),  f2bf(a.w)  };
    s4v pp = { f2bf(p0.x), f2bf(p0.y), f2bf(p0.z), f2bf(p0.w) };
    *(s4v*)&uA[lw] = au;
    *(s4v*)&pB[lw] = pp;
    __syncthreads();
    if (c < 23) {                     // prefetch next chunk (overlaps MFMA)
      ru = *(const float4*)(ubase + (c + 1) * 32);
      rp = *(const float4*)(pbase + (c + 1) * 32);
    }
    s8v af  = *(const s8v*)ab;
    s8v bf0 = *(const s8v*)bb;
    s8v bf1 = *(const s8v*)(bb + 16 * LDU);
    acc0 = __builtin_amdgcn_mfma_f32_16x16x32_bf16(af, bf0, acc0, 0, 0, 0);
    acc1 = __builtin_amdgcn_mfma_f32_16x16x32_bf16(af, bf1, acc1, 0, 0, 0);
  }

  // row sumsq reductions: 8 threads/row are adjacent lanes
  ssu += __shfl_xor(ssu, 4); ssu += __shfl_xor(ssu, 2); ssu += __shfl_xor(ssu, 1);
  ssp += __shfl_xor(ssp, 4); ssp += __shfl_xor(ssp, 2); ssp += __shfl_xor(ssp, 1);
  if ((t & 7) == 0) {
    s_inu[r] = 1.f / fmaxf(sqrtf(ssu), 1e-8f);
    s_inp[r] = 1.f / fmaxf(sqrtf(ssp), 1e-8f);
  }
  __syncthreads();

  // epilogue: scale, store bf16 C[b][half*64+i][j]
  // D layout (verified m89/m91): col = lane&15, row = (lane>>4)*4 + reg
  const int cl = l & 15;
  const int rq = (l >> 4) * 4;
#pragma unroll
  for (int jt = 0; jt < 2; ++jt) {
    int j = jp * 32 + jt * 16 + cl;
    float sj = s_inp[j];
    f4v a = (jt == 0) ? acc0 : acc1;
#pragma unroll
    for (int rr = 0; rr < 4; ++rr) {
      int il = it * 16 + rq + rr;     // local row 0..63
      float v = a[rr] * s_inu[il] * sj;
      Cbf[((size_t)b * Un + half * 64 + il) * Pn + j] = (ushort)f2bf(v);
    }
  }
}

// ---------------------------------------------------------------------------
// Kernel 3: logits GEMM, M=256, N=192, K=8192, split-K (KC=16).
// 64-wide k-stages: 8 stages of K=64 -> half the barrier drains of round 3.
// ---------------------------------------------------------------------------
__global__ void __launch_bounds__(256) phaseB(const ushort* __restrict__ Cbf,
                                              const ushort* __restrict__ Wbf,
                                              float* __restrict__ partial) {
  const int kc = blockIdx.x;
  const int mt = blockIdx.y;
  const int nt = blockIdx.z;
  const int t = threadIdx.x;
  const int w = t >> 6, l = t & 63;

  __shared__ short Ab[64 * LDB];
  __shared__ short Bb[64 * LDB];

  const int row = t >> 2;          // 0..63
  const int k16 = (t & 3) * 16;    // 16 elems per thread per stage-row

  f4v zero4 = {0.f, 0.f, 0.f, 0.f};
  f4v acc[4] = {zero4, zero4, zero4, zero4};

  const ushort* Ag = Cbf + (size_t)(mt * 64 + row) * 8192 + kc * 512 + k16;
  const ushort* Bg = Wbf + (size_t)(nt * 64 + row) * 8192 + kc * 512 + k16;
  const int m  = l & 15;
  const int ko = (l >> 4) * 8;

  for (int c = 0; c < 8; ++c) {
    s8v av0 = *(const s8v*)(Ag + c * 64);
    s8v av1 = *(const s8v*)(Ag + c * 64 + 8);
    s8v bv0 = *(const s8v*)(Bg + c * 64);
    s8v bv1 = *(const s8v*)(Bg + c * 64 + 8);
    __syncthreads();
    *(s8v*)&Ab[row * LDB + k16]     = av0;
    *(s8v*)&Ab[row * LDB + k16 + 8] = av1;
    *(s8v*)&Bb[row * LDB + k16]     = bv0;
    *(s8v*)&Bb[row * LDB + k16 + 8] = bv1;
    __syncthreads();
#pragma unroll
    for (int ks = 0; ks < 2; ++ks) {
      s8v af = *(const s8v*)&Ab[(16 * w + m) * LDB + ks * 32 + ko];
#pragma unroll
      for (int jt = 0; jt < 4; ++jt) {
        s8v bf = *(const s8v*)&Bb[(16 * jt + m) * LDB + ks * 32 + ko];
        acc[jt] = __builtin_amdgcn_mfma_f32_16x16x32_bf16(af, bf, acc[jt], 0, 0, 0);
      }
    }
  }

  const int rq = (l >> 4) * 4;
#pragma unroll
  for (int jt = 0; jt < 4; ++jt) {
    int og = nt * 64 + 16 * jt + (l & 15);
#pragma unroll
    for (int r = 0; r < 4; ++r) {
      int bg = mt * 64 + 16 * w + rq + r;
      partial[((size_t)kc * Bn + bg) * Ototal + og] = acc[jt][r];
    }
  }
}

// ---------------------------------------------------------------------------
// Kernel 4: reduce split-K partials + bias + dual-group softmax.
// ---------------------------------------------------------------------------
__global__ void __launch_bounds__(192) phaseC(const float* __restrict__ partial,
                                              const float* __restrict__ b_utt,
                                              const float* __restrict__ b_ph,
                                              float* __restrict__ out) {
  const int b = blockIdx.x;
  const int t = threadIdx.x;      // 0..191
  const int w = t >> 6, l = t & 63;

  float v = 0.f;
#pragma unroll
  for (int kc = 0; kc < KC; ++kc)
    v += partial[((size_t)kc * Bn + b) * Ototal + t];
  v += (t < Un) ? b_utt[t] : b_ph[t - Un];

  __shared__ float red[3];
  float mx = v;
  for (int o = 32; o >= 1; o >>= 1) mx = fmaxf(mx, __shfl_xor(mx, o));
  if (l == 0) red[w] = mx;
  __syncthreads();
  float gmax = (t < Un) ? fmaxf(red[0], red[1]) : red[2];
  float e = expf(v - gmax);
  float s = e;
  for (int o = 32; o >= 1; o >>= 1) s += __shfl_xor(s, o);
  __syncthreads();
  if (l == 0) red[w] = s;
  __syncthreads();
  float gs = (t < Un) ? (red[0] + red[1]) : red[2];
  float r = e / gs;
  if (t < Un) out[(size_t)b * Un + t] = r;
  else        out[(size_t)Bn * Un + (size_t)b * Pn + (t - Un)] = r;
}

// ---------------------------------------------------------------------------
extern "C" void kernel_launch(void* const* d_in, const int* in_sizes, int n_in,
                              void* d_out, int out_size, void* d_ws, size_t ws_size,
                              hipStream_t stream) {
  const float* utt   = (const float*)d_in[0];  // [128,256,768]
  const float* ph    = (const float*)d_in[1];  // [64,256,768]
  const float* w_utt = (const float*)d_in[2];  // [128,128,64]
  const float* b_utt = (const float*)d_in[3];  // [128]
  const float* w_ph  = (const float*)d_in[4];  // [64,64,128]
  const float* b_ph  = (const float*)d_in[5];  // [64]

  char* ws = (char*)d_ws;
  ushort* Cbf     = (ushort*)(ws);                 // 256*128*64*2  = 4 MiB
  ushort* Wbf     = (ushort*)(ws + 4194304);       // 192*8192*2   = 3 MiB
  float*  partial = (float*)(ws + 7340032);        // 16*256*192*4 = 3 MiB

  convW <<<dim3(4096 + 64), dim3(256), 0, stream>>>(w_utt, w_ph, Wbf);
  phaseA<<<dim3(2 * Bn), dim3(512), 0, stream>>>(utt, ph, Cbf);
  phaseB<<<dim3(KC, 4, 3), dim3(256), 0, stream>>>(Cbf, Wbf, partial);
  phaseC<<<dim3(Bn), dim3(192), 0, stream>>>(partial, b_utt, b_ph, (float*)d_out);
}